// Round 1
// baseline (78.929 us; speedup 1.0000x reference)
//
#include <hip/hip_runtime.h>
#include <math.h>

// IntraVolume_Attention collapses algebraically:
//   scores[b,v,f,g] = c * x[b,v,f] * x[b,v,g],  c = dot(w_q,w_k)/sqrt(128)
//   out[b,v,d] = w_v[d] * mean_f( softmax-weighted-mean_g(x) with logits c*x_f*x_g )
// So: per (b,v) row of F=512 values, 512 independent 1-D softmaxes over the
// same row, averaged, then an outer product with w_v (d_model=128).

#define F_DIM 512
#define D_MODEL 128

__global__ __launch_bounds__(512) void intravol_attn_kernel(
    const float* __restrict__ x,    // [256, 512] flattened (B*V, F)
    const float* __restrict__ wq,   // [128]
    const float* __restrict__ wk,   // [128]
    const float* __restrict__ wv,   // [128]
    float* __restrict__ out)        // [256, 128]
{
    __shared__ float xs[F_DIM];
    __shared__ float red[512];
    __shared__ float s_c, s_xmax, s_xmin;

    const int bv  = blockIdx.x;
    const int tid = threadIdx.x;

    // Stage this (b,v)'s x-row in LDS.
    xs[tid] = x[bv * F_DIM + tid];

    // --- c = dot(w_q, w_k) (redundant per block; 1 KB, L2-resident) ---
    red[tid] = (tid < D_MODEL) ? wq[tid] * wk[tid] : 0.0f;
    __syncthreads();
    for (int s = 256; s > 0; s >>= 1) {
        if (tid < s) red[tid] += red[tid + s];
        __syncthreads();
    }
    if (tid == 0) s_c = red[0] * 0.08838834764831845f; // 1/sqrt(128)
    __syncthreads();

    // --- row max (for softmax stability, matches jax.nn.softmax) ---
    red[tid] = xs[tid];
    __syncthreads();
    for (int s = 256; s > 0; s >>= 1) {
        if (tid < s) red[tid] = fmaxf(red[tid], red[tid + s]);
        __syncthreads();
    }
    if (tid == 0) s_xmax = red[0];
    __syncthreads();

    // --- row min ---
    red[tid] = xs[tid];
    __syncthreads();
    for (int s = 256; s > 0; s >>= 1) {
        if (tid < s) red[tid] = fminf(red[tid], red[tid + s]);
        __syncthreads();
    }
    if (tid == 0) s_xmin = red[0];
    __syncthreads();

    // --- per-f softmax-weighted mean over g ---
    // logits: a * x_g with a = c * x_f; max logit = a*xmax (a>=0) or a*xmin.
    const float LOG2E = 1.4426950408889634f;
    const float a  = s_c * xs[tid];
    const float m  = (a >= 0.0f) ? a * s_xmax : a * s_xmin;
    const float a2 = a * LOG2E;        // fold log2(e) into the fma
    const float m2 = m * LOG2E;

    float den = 0.0f, num = 0.0f;
    #pragma unroll 8
    for (int g = 0; g < F_DIM; ++g) {
        const float xg = xs[g];                 // LDS broadcast (same addr all lanes)
        const float e  = exp2f(fmaf(a2, xg, -m2));
        den += e;
        num = fmaf(e, xg, num);
    }
    const float s_f = num / den;

    // --- mean over f: block sum of s_f ---
    red[tid] = s_f;
    __syncthreads();
    for (int s = 256; s > 0; s >>= 1) {
        if (tid < s) red[tid] += red[tid + s];
        __syncthreads();
    }

    // --- epilogue: out[bv, d] = (sum_f s_f / F) * w_v[d] ---
    if (tid < D_MODEL) {
        const float t = red[0] * (1.0f / (float)F_DIM);
        out[bv * D_MODEL + tid] = t * wv[tid];
    }
}

extern "C" void kernel_launch(void* const* d_in, const int* in_sizes, int n_in,
                              void* d_out, int out_size, void* d_ws, size_t ws_size,
                              hipStream_t stream) {
    const float* x  = (const float*)d_in[0];  // [8,32,512]
    const float* wq = (const float*)d_in[1];  // [1,128]
    const float* wk = (const float*)d_in[2];  // [1,128]
    const float* wv = (const float*)d_in[3];  // [1,128]
    float* out = (float*)d_out;               // [8,32,128]

    intravol_attn_kernel<<<256, 512, 0, stream>>>(x, wq, wk, wv, out);
}

// Round 2
// 69.246 us; speedup vs baseline: 1.1398x; 1.1398x over previous
//
#include <hip/hip_runtime.h>
#include <math.h>

// IntraVolume_Attention collapses algebraically:
//   scores[b,v,f,g] = c * x[b,v,f] * x[b,v,g],  c = dot(w_q,w_k)/sqrt(128)
//   out[b,v,d] = w_v[d] * mean_f( softmax_weighted_mean_g(x) with logits c*x_f*x_g )
// Per (b,v) row of F=512: 512 1-D softmaxes over the same row, averaged,
// then scaled by w_v. 67M exps total, ~640 KB HBM traffic -> exp-pipe bound.
//
// Structure: 256 blocks (one per row) x 1024 threads (2 threads per f, each
// covering half the g-range) = 4 waves/SIMD for latency hiding. The softmax
// max m = a*xmax (a>=0) or a*xmin is global per f, so half-sums combine exactly.

#if __has_builtin(__builtin_amdgcn_exp2f)
#define EXP2(x) __builtin_amdgcn_exp2f(x)   // raw v_exp_f32, no denorm guard
#else
#define EXP2(x) exp2f(x)
#endif

#define F_DIM 512
#define D_MODEL 128

__global__ __launch_bounds__(1024) void intravol_attn_kernel(
    const float* __restrict__ x,    // [256, 512]
    const float* __restrict__ wq,   // [128]
    const float* __restrict__ wk,   // [128]
    const float* __restrict__ wv,   // [128]
    float* __restrict__ out)        // [256, 128]
{
    __shared__ float xs[F_DIM];
    __shared__ float pden[1024], pnum[1024];
    __shared__ float wmax[8], wmin[8], wsum[16];
    __shared__ float s_c, s_xmax, s_xmin;

    const int bv   = blockIdx.x;
    const int tid  = threadIdx.x;
    const int lane = tid & 63;
    const int wave = tid >> 6;

    // Threads 0..511 stage the x-row; keep own value in register for reduction.
    float xv = 0.0f;
    if (tid < F_DIM) { xv = x[bv * F_DIM + tid]; xs[tid] = xv; }

    // Waves 0..7: shuffle-reduce max/min of the row (no syncthreads needed
    // inside a wave). Wave 8 concurrently computes c = dot(wq,wk)/sqrt(128).
    if (wave < 8) {
        float mx = xv, mn = xv;
        for (int o = 32; o > 0; o >>= 1) {
            mx = fmaxf(mx, __shfl_down(mx, o));
            mn = fminf(mn, __shfl_down(mn, o));
        }
        if (lane == 0) { wmax[wave] = mx; wmin[wave] = mn; }
    } else if (wave == 8) {
        float d = wq[lane] * wk[lane] + wq[lane + 64] * wk[lane + 64];
        for (int o = 32; o > 0; o >>= 1) d += __shfl_down(d, o);
        if (lane == 0) s_c = d * 0.08838834764831845f; // 1/sqrt(128)
    }
    __syncthreads();
    if (tid == 0) {
        float M = wmax[0], m_ = wmin[0];
        for (int i = 1; i < 8; ++i) { M = fmaxf(M, wmax[i]); m_ = fminf(m_, wmin[i]); }
        s_xmax = M; s_xmin = m_;
    }
    __syncthreads();

    // Main loop: thread pair (f, f+512) handles f's softmax over g-halves.
    const float LOG2E = 1.4426950408889634f;
    const int   f  = tid & (F_DIM - 1);
    const int   g0 = (tid >> 9) << 8;          // 0 or 256
    const float a2 = s_c * xs[f] * LOG2E;
    const float m2 = (a2 >= 0.0f) ? a2 * s_xmax : a2 * s_xmin; // = LOG2E * true max logit

    float den = 0.0f, num = 0.0f;
    #pragma unroll 8
    for (int g = g0; g < g0 + 256; ++g) {
        const float xg = xs[g];               // uniform addr -> LDS broadcast
        const float e  = EXP2(fmaf(a2, xg, -m2));
        den += e;
        num = fmaf(e, xg, num);
    }
    pden[tid] = den; pnum[tid] = num;
    __syncthreads();

    // Combine g-halves, s_f = num/den, then block-sum s_f over the 512 f's.
    float s_f = 0.0f;
    if (tid < F_DIM) {
        const float d = pden[tid] + pden[tid + F_DIM];
        const float n = pnum[tid] + pnum[tid + F_DIM];
        s_f = n / d;
    }
    float t = s_f;
    for (int o = 32; o > 0; o >>= 1) t += __shfl_down(t, o);
    if (lane == 0) wsum[wave] = t;            // waves 8..15 contribute zeros
    __syncthreads();

    if (tid < D_MODEL) {
        float total = 0.0f;
        for (int i = 0; i < 16; ++i) total += wsum[i];
        out[bv * D_MODEL + tid] = total * (1.0f / (float)F_DIM) * wv[tid];
    }
}

extern "C" void kernel_launch(void* const* d_in, const int* in_sizes, int n_in,
                              void* d_out, int out_size, void* d_ws, size_t ws_size,
                              hipStream_t stream) {
    const float* x  = (const float*)d_in[0];  // [8,32,512]
    const float* wq = (const float*)d_in[1];  // [1,128]
    const float* wk = (const float*)d_in[2];  // [1,128]
    const float* wv = (const float*)d_in[3];  // [1,128]
    float* out = (float*)d_out;               // [8,32,128]

    intravol_attn_kernel<<<256, 1024, 0, stream>>>(x, wq, wk, wv, out);
}

// Round 3
// 67.451 us; speedup vs baseline: 1.1702x; 1.0266x over previous
//
#include <hip/hip_runtime.h>
#include <math.h>

// IntraVolume_Attention collapses algebraically:
//   scores[b,v,f,g] = c * x[b,v,f] * x[b,v,g],  c = dot(w_q,w_k)/sqrt(128)
//   out[b,v,d] = w_v[d] * mean_f( softmax_weighted_mean_g(x) with logits c*x_f*x_g )
// 67M exps total, ~640 KB HBM -> transcendental-pipe bound (floor ~3.4 us).
//
// R2 lesson: 1 ds_read_b32 per exp made the loop LDS/issue bound (~29 us).
// Now: 1024 thr = 128 f-quads x 8 g-slices. Each thread: 4 f's in registers,
// 64-g slice via 16 ds_read_b128 -> each LDS read feeds 16 exps.
// Per-CU: LDS 3.1k cyc, exp 8.2k cyc/SIMD (binding), VALU 6.1k (co-issues).

#if __has_builtin(__builtin_amdgcn_exp2f)
#define EXP2(x) __builtin_amdgcn_exp2f(x)   // raw v_exp_f32
#else
#define EXP2(x) exp2f(x)
#endif

#define F_DIM 512
#define NF 4            // f's per thread
#define NSLICE 8        // g-slices per row
#define GS (F_DIM / NSLICE)  // 64 g's per slice

__global__ __launch_bounds__(1024) void intravol_attn_kernel(
    const float* __restrict__ x,    // [256, 512]
    const float* __restrict__ wq,   // [128]
    const float* __restrict__ wk,   // [128]
    const float* __restrict__ wv,   // [128]
    float* __restrict__ out)        // [256, 128]
{
    __shared__ __align__(16) float xs[F_DIM];
    __shared__ __align__(16) float pden[NSLICE * F_DIM];  // 16 KB
    __shared__ __align__(16) float pnum[NSLICE * F_DIM];  // 16 KB
    __shared__ float wmax[8], wmin[8], wsum[16];
    __shared__ float s_c, s_xmax, s_xmin;

    const int bv   = blockIdx.x;
    const int tid  = threadIdx.x;
    const int lane = tid & 63;
    const int wave = tid >> 6;

    // Stage the x-row (threads 0..511); keep value for the max/min reduce.
    float xv = 0.0f;
    if (tid < F_DIM) { xv = x[bv * F_DIM + tid]; xs[tid] = xv; }

    // Waves 0..7: row max/min via shuffles. Wave 8: c = dot(wq,wk)/sqrt(128).
    if (wave < 8) {
        float mx = xv, mn = xv;
        for (int o = 32; o > 0; o >>= 1) {
            mx = fmaxf(mx, __shfl_down(mx, o));
            mn = fminf(mn, __shfl_down(mn, o));
        }
        if (lane == 0) { wmax[wave] = mx; wmin[wave] = mn; }
    } else if (wave == 8) {
        float d = wq[lane] * wk[lane] + wq[lane + 64] * wk[lane + 64];
        for (int o = 32; o > 0; o >>= 1) d += __shfl_down(d, o);
        if (lane == 0) s_c = d * 0.08838834764831845f; // 1/sqrt(128)
    }
    __syncthreads();
    if (tid == 0) {
        float M = wmax[0], m_ = wmin[0];
        for (int i = 1; i < 8; ++i) { M = fmaxf(M, wmax[i]); m_ = fminf(m_, wmin[i]); }
        s_xmax = M; s_xmin = m_;
    }
    __syncthreads();

    // Partition: f-quad q = tid&127 -> f = 4q..4q+3 ; g-slice s = tid>>7.
    const float LOG2E = 1.4426950408889634f;
    const int q  = tid & 127;
    const int sl = tid >> 7;
    const int f0 = q << 2;

    float a2[NF], m2n[NF], den[NF], num[NF];
    #pragma unroll
    for (int k = 0; k < NF; ++k) {
        const float a = s_c * xs[f0 + k] * LOG2E;
        a2[k]  = a;
        m2n[k] = -((a >= 0.0f) ? a * s_xmax : a * s_xmin); // -LOG2E*max_logit
        den[k] = 0.0f;
        num[k] = 0.0f;
    }

    const float4* xs4 = (const float4*)&xs[sl * GS];
    #pragma unroll 4
    for (int i = 0; i < GS / 4; ++i) {          // 16 ds_read_b128
        const float4 v = xs4[i];
        const float xg_[4] = { v.x, v.y, v.z, v.w };
        #pragma unroll
        for (int j = 0; j < 4; ++j) {
            const float xg = xg_[j];
            #pragma unroll
            for (int k = 0; k < NF; ++k) {
                const float e = EXP2(fmaf(a2[k], xg, m2n[k]));
                den[k] += e;
                num[k] = fmaf(e, xg, num[k]);
            }
        }
    }

    // Partials laid out [slice][f]; combine-read below is 2-way-bank (free).
    *(float4*)&pden[sl * F_DIM + f0] = make_float4(den[0], den[1], den[2], den[3]);
    *(float4*)&pnum[sl * F_DIM + f0] = make_float4(num[0], num[1], num[2], num[3]);
    __syncthreads();

    // s_f = num/den per f, then block-sum over the 512 f's.
    float s_f = 0.0f;
    if (tid < F_DIM) {
        float d = 0.0f, n = 0.0f;
        #pragma unroll
        for (int s2 = 0; s2 < NSLICE; ++s2) {
            d += pden[s2 * F_DIM + tid];
            n += pnum[s2 * F_DIM + tid];
        }
        s_f = n / d;
    }
    float t = s_f;
    for (int o = 32; o > 0; o >>= 1) t += __shfl_down(t, o);
    if (lane == 0) wsum[wave] = t;              // waves 8..15 contribute zeros
    __syncthreads();

    if (tid < 128) {
        float total = 0.0f;
        #pragma unroll
        for (int i = 0; i < 16; ++i) total += wsum[i];
        out[bv * 128 + tid] = total * (1.0f / (float)F_DIM) * wv[tid];
    }
}

extern "C" void kernel_launch(void* const* d_in, const int* in_sizes, int n_in,
                              void* d_out, int out_size, void* d_ws, size_t ws_size,
                              hipStream_t stream) {
    const float* x  = (const float*)d_in[0];  // [8,32,512]
    const float* wq = (const float*)d_in[1];  // [1,128]
    const float* wk = (const float*)d_in[2];  // [1,128]
    const float* wv = (const float*)d_in[3];  // [1,128]
    float* out = (float*)d_out;               // [8,32,128]

    intravol_attn_kernel<<<256, 1024, 0, stream>>>(x, wq, wk, wv, out);
}